// Round 1
// baseline (1611.377 us; speedup 1.0000x reference)
//
#include <hip/hip_runtime.h>
#include <hip/hip_bf16.h>

typedef __bf16 bf16x8 __attribute__((ext_vector_type(8)));
typedef __bf16 bf16x4 __attribute__((ext_vector_type(4)));
typedef float f32x4 __attribute__((ext_vector_type(4)));

// Problem constants
#define SEQ 512
#define BATCH 32
#define DIM 1024
#define NHEAD 16
#define MROWS (SEQ * BATCH)   // 16384

__device__ __forceinline__ void gload16(const void* g, void* s) {
    __builtin_amdgcn_global_load_lds((const __attribute__((address_space(1))) void*)g,
                                     (__attribute__((address_space(3))) void*)s, 16, 0, 0);
}

// ---------------- f32 -> bf16 convert ----------------
__global__ __launch_bounds__(256) void cvt_kernel(const float* __restrict__ src,
                                                  __bf16* __restrict__ dst, int n) {
    int i = (blockIdx.x * 256 + threadIdx.x) * 4;
    if (i < n) {
        float4 v = *(const float4*)(src + i);
        bf16x4 o;
        o[0] = (__bf16)v.x; o[1] = (__bf16)v.y; o[2] = (__bf16)v.z; o[3] = (__bf16)v.w;
        *(bf16x4*)&dst[i] = o;
    }
}

// ---------------- LayerNorm (row of 1024) -> bf16 ----------------
__global__ __launch_bounds__(256) void ln_kernel(const float* __restrict__ x,
                                                 const float* __restrict__ w,
                                                 const float* __restrict__ b,
                                                 __bf16* __restrict__ out) {
    int row = blockIdx.x, t = threadIdx.x;
    const float4* xr = (const float4*)(x + (size_t)row * DIM);
    float4 v = xr[t];
    float s  = v.x + v.y + v.z + v.w;
    float ss = v.x * v.x + v.y * v.y + v.z * v.z + v.w * v.w;
#pragma unroll
    for (int o = 1; o < 64; o <<= 1) { s += __shfl_xor(s, o); ss += __shfl_xor(ss, o); }
    __shared__ float red[8];
    if ((t & 63) == 0) { red[t >> 6] = s; red[4 + (t >> 6)] = ss; }
    __syncthreads();
    s  = red[0] + red[1] + red[2] + red[3];
    ss = red[4] + red[5] + red[6] + red[7];
    float mu = s * (1.f / DIM);
    float rs = rsqrtf(ss * (1.f / DIM) - mu * mu + 1e-5f);
    int c = t * 4;
    bf16x4 o4;
    o4[0] = (__bf16)((v.x - mu) * rs * w[c + 0] + b[c + 0]);
    o4[1] = (__bf16)((v.y - mu) * rs * w[c + 1] + b[c + 1]);
    o4[2] = (__bf16)((v.z - mu) * rs * w[c + 2] + b[c + 2]);
    o4[3] = (__bf16)((v.w - mu) * rs * w[c + 3] + b[c + 3]);
    *(bf16x4*)&out[(size_t)row * DIM + c] = o4;
}

// ---------------- GEMM: out[M,N] = A[M,K] @ W[N,K]^T + bias (+act/+res) ----------------
// MODE 0: bf16 out;  1: bf16 out + quickGELU;  2: f32 out + residual
template <int MODE>
__global__ __launch_bounds__(256) void gemm_kernel(const __bf16* __restrict__ A,
                                                   const __bf16* __restrict__ W,
                                                   const float* __restrict__ bias,
                                                   const float* res, void* out,
                                                   int M, int N, int K) {
    __shared__ __bf16 As[128 * 32];
    __shared__ __bf16 Bs[128 * 32];
    int t = threadIdx.x, l = t & 63, wv = t >> 6;
    int m0 = blockIdx.y * 128, n0 = blockIdx.x * 128;
    int wm = (wv >> 1) * 64, wn = (wv & 1) * 64;
    f32x4 acc[4][4];
#pragma unroll
    for (int i = 0; i < 4; i++)
#pragma unroll
        for (int j = 0; j < 4; j++) acc[i][j] = (f32x4){0.f, 0.f, 0.f, 0.f};

    const __bf16* Ab = A + (size_t)m0 * K;
    const __bf16* Wb = W + (size_t)n0 * K;
    int sr = t >> 2, sc0 = (t & 3) * 8;
    int lr = l & 15, lk = (l >> 4) * 8;

    for (int k0 = 0; k0 < K; k0 += 32) {
        gload16(Ab + (size_t)sr * K + k0 + sc0,        As + t * 8);
        gload16(Ab + (size_t)(sr + 64) * K + k0 + sc0, As + 2048 + t * 8);
        gload16(Wb + (size_t)sr * K + k0 + sc0,        Bs + t * 8);
        gload16(Wb + (size_t)(sr + 64) * K + k0 + sc0, Bs + 2048 + t * 8);
        __syncthreads();
        bf16x8 af[4], bfr[4];
#pragma unroll
        for (int i = 0; i < 4; i++) af[i]  = *(const bf16x8*)&As[(wm + i * 16 + lr) * 32 + lk];
#pragma unroll
        for (int j = 0; j < 4; j++) bfr[j] = *(const bf16x8*)&Bs[(wn + j * 16 + lr) * 32 + lk];
#pragma unroll
        for (int i = 0; i < 4; i++)
#pragma unroll
            for (int j = 0; j < 4; j++)
                acc[i][j] = __builtin_amdgcn_mfma_f32_16x16x32_bf16(af[i], bfr[j], acc[i][j], 0, 0, 0);
        __syncthreads();
    }

#pragma unroll
    for (int j = 0; j < 4; j++) {
        int col = n0 + wn + j * 16 + lr;
        float bv = bias[col];
#pragma unroll
        for (int i = 0; i < 4; i++) {
#pragma unroll
            for (int r = 0; r < 4; r++) {
                int row = m0 + wm + i * 16 + (l >> 4) * 4 + r;
                float v = acc[i][j][r] + bv;
                if (MODE == 1) v = v / (1.f + expf(-1.702f * v));
                size_t idx = (size_t)row * N + col;
                if (MODE == 2) ((float*)out)[idx] = v + res[idx];
                else           ((__bf16*)out)[idx] = (__bf16)v;
            }
        }
    }
}

// ---------------- Fused attention ----------------
// Block per (b, q-tile of 16). Loops 16 heads: scores MFMA -> softmax -> P@V MFMA.
// Accumulates mean-over-heads attention weights in LDS, writes once.
__global__ __launch_bounds__(256) void attn_kernel(const __bf16* __restrict__ qkv,
                                                   __bf16* __restrict__ ctx,
                                                   float* __restrict__ attnw) {
    __shared__ float  sc[16 * 512];     // 32 KB scores
    __shared__ float  aw[16 * 512];     // 32 KB attn-weight accumulator
    __shared__ __bf16 p16[16 * 512];    // 16 KB probabilities bf16
    __shared__ __bf16 kv[512 * 64];     // 64 KB K (then V^T)
    __shared__ __bf16 qt[16 * 64];      //  2 KB Q tile

    int t = threadIdx.x, l = t & 63, wv = t >> 6;
    int bb = blockIdx.x >> 5;           // batch index 0..31
    int q0 = (blockIdx.x & 31) * 16;    // q-tile start
    int lr = l & 15, lk = (l >> 4) * 8;
    int r = t >> 4, cb = t & 15;        // softmax: row, col-base (16 thr/row)

    for (int i = t; i < 16 * 512; i += 256) aw[i] = 0.f;

    for (int h = 0; h < NHEAD; ++h) {
        __syncthreads();  // prev-iter readers of kv/p16 done
        // stage K_h : [512][64]
#pragma unroll 4
        for (int it = 0; it < 16; ++it) {
            int s = it * 32 + (t >> 3), d0 = (t & 7) * 8;
            bf16x8 kk = *(const bf16x8*)&qkv[(size_t)(s * BATCH + bb) * 3072 + 1024 + h * 64 + d0];
            *(bf16x8*)&kv[s * 64 + d0] = kk;
        }
        // stage Q tile : [16][64]
        if (t < 128) {
            int qq = t >> 3, d0 = (t & 7) * 8;
            *(bf16x8*)&qt[qq * 64 + d0] =
                *(const bf16x8*)&qkv[(size_t)((q0 + qq) * BATCH + bb) * 3072 + h * 64 + d0];
        }
        __syncthreads();

        // scores: wave wv covers key cols wv*128 .. +127
        bf16x8 a0 = *(const bf16x8*)&qt[lr * 64 + lk];
        bf16x8 a1 = *(const bf16x8*)&qt[lr * 64 + 32 + lk];
#pragma unroll
        for (int nt = 0; nt < 8; ++nt) {
            int nb = wv * 128 + nt * 16;
            f32x4 acc = (f32x4){0.f, 0.f, 0.f, 0.f};
            bf16x8 b0 = *(const bf16x8*)&kv[(nb + lr) * 64 + lk];
            bf16x8 b1 = *(const bf16x8*)&kv[(nb + lr) * 64 + 32 + lk];
            acc = __builtin_amdgcn_mfma_f32_16x16x32_bf16(a0, b0, acc, 0, 0, 0);
            acc = __builtin_amdgcn_mfma_f32_16x16x32_bf16(a1, b1, acc, 0, 0, 0);
#pragma unroll
            for (int rr = 0; rr < 4; ++rr)
                sc[((l >> 4) * 4 + rr) * 512 + nb + lr] = acc[rr] * 0.125f;
        }
        __syncthreads();

        // softmax: 16 threads per row, 32 cols each (stride 16)
        float ev[32];
        float mx = -1e30f;
#pragma unroll
        for (int j = 0; j < 32; ++j) { ev[j] = sc[r * 512 + cb + j * 16]; mx = fmaxf(mx, ev[j]); }
#pragma unroll
        for (int o = 1; o < 16; o <<= 1) mx = fmaxf(mx, __shfl_xor(mx, o));
        float sum = 0.f;
#pragma unroll
        for (int j = 0; j < 32; ++j) { ev[j] = expf(ev[j] - mx); sum += ev[j]; }
#pragma unroll
        for (int o = 1; o < 16; o <<= 1) sum += __shfl_xor(sum, o);
        float inv = 1.f / sum;
#pragma unroll
        for (int j = 0; j < 32; ++j) {
            float p = ev[j] * inv;
            int c = cb + j * 16;
            p16[r * 512 + c] = (__bf16)p;
            aw[r * 512 + c] += p * (1.f / NHEAD);
        }

        // stage V_h transposed into kv: Vt[d][s]  (scores reads of kv completed at barrier above)
#pragma unroll 4
        for (int it = 0; it < 16; ++it) {
            int s = it * 32 + (t >> 3), d0 = (t & 7) * 8;
            bf16x8 vv = *(const bf16x8*)&qkv[(size_t)(s * BATCH + bb) * 3072 + 2048 + h * 64 + d0];
#pragma unroll
            for (int e = 0; e < 8; ++e) kv[(d0 + e) * 512 + s] = vv[e];
        }
        __syncthreads();

        // ctx tile: wave wv computes head-dim cols wv*16 .. +15, K=512
        f32x4 cacc = (f32x4){0.f, 0.f, 0.f, 0.f};
#pragma unroll
        for (int ks = 0; ks < 16; ++ks) {
            bf16x8 ap = *(const bf16x8*)&p16[lr * 512 + ks * 32 + lk];
            bf16x8 bvv = *(const bf16x8*)&kv[(wv * 16 + lr) * 512 + ks * 32 + lk];
            cacc = __builtin_amdgcn_mfma_f32_16x16x32_bf16(ap, bvv, cacc, 0, 0, 0);
        }
#pragma unroll
        for (int rr = 0; rr < 4; ++rr) {
            int qr = q0 + (l >> 4) * 4 + rr;
            ctx[(size_t)(qr * BATCH + bb) * DIM + h * 64 + wv * 16 + lr] = (__bf16)cacc[rr];
        }
    }

    // write mean attention weights (thread-owned elements, no sync needed)
#pragma unroll
    for (int j = 0; j < 32; ++j)
        attnw[(size_t)bb * (SEQ * SEQ) + (size_t)(q0 + r) * SEQ + cb + j * 16] =
            aw[r * 512 + cb + j * 16];
}

// ---------------- launch ----------------
extern "C" void kernel_launch(void* const* d_in, const int* in_sizes, int n_in,
                              void* d_out, int out_size, void* d_ws, size_t ws_size,
                              hipStream_t stream) {
    const float* x    = (const float*)d_in[0];
    const float* ln1w = (const float*)d_in[1];
    const float* ln1b = (const float*)d_in[2];
    const float* ipw  = (const float*)d_in[3];
    const float* ipb  = (const float*)d_in[4];
    const float* outw = (const float*)d_in[5];
    const float* outb = (const float*)d_in[6];
    const float* ln2w = (const float*)d_in[7];
    const float* ln2b = (const float*)d_in[8];
    const float* fcw  = (const float*)d_in[9];
    const float* fcb  = (const float*)d_in[10];
    const float* pjw  = (const float*)d_in[11];
    const float* pjb  = (const float*)d_in[12];

    float* xout  = (float*)d_out;                       // (S,B,D) final
    float* awout = xout + (size_t)MROWS * DIM;          // (B,S,S)

    // workspace layout (bf16 elems)
    __bf16* wip  = (__bf16*)d_ws;                       // 3072x1024
    __bf16* wout_ = wip + 3145728;                      // 1024x1024
    __bf16* wfc  = wout_ + 1048576;                     // 4096x1024
    __bf16* wpj  = wfc + 4194304;                       // 1024x4096
    __bf16* hbuf = wpj + 4194304;                       // 16384x1024 (ln1/ln2 out)
    __bf16* big  = hbuf + (size_t)MROWS * DIM;          // 67108864-elem region
    __bf16* qkv  = big;                                 // 16384x3072
    __bf16* ctxb = big + (size_t)MROWS * 3072;          // 16384x1024
    __bf16* mg   = big;                                 // 16384x4096 (aliases qkv+ctx, used later)

    cvt_kernel<<<3072, 256, 0, stream>>>(ipw,  wip,   3145728);
    cvt_kernel<<<1024, 256, 0, stream>>>(outw, wout_, 1048576);
    cvt_kernel<<<4096, 256, 0, stream>>>(fcw,  wfc,   4194304);
    cvt_kernel<<<4096, 256, 0, stream>>>(pjw,  wpj,   4194304);

    ln_kernel<<<MROWS, 256, 0, stream>>>(x, ln1w, ln1b, hbuf);

    gemm_kernel<0><<<dim3(24, 128), 256, 0, stream>>>(hbuf, wip, ipb, nullptr, qkv,
                                                      MROWS, 3072, 1024);

    attn_kernel<<<BATCH * 32, 256, 0, stream>>>(qkv, ctxb, awout);

    gemm_kernel<2><<<dim3(8, 128), 256, 0, stream>>>(ctxb, wout_, outb, x, xout,
                                                     MROWS, 1024, 1024);

    ln_kernel<<<MROWS, 256, 0, stream>>>(xout, ln2w, ln2b, hbuf);

    gemm_kernel<1><<<dim3(32, 128), 256, 0, stream>>>(hbuf, wfc, fcb, nullptr, mg,
                                                      MROWS, 4096, 1024);

    gemm_kernel<2><<<dim3(8, 128), 256, 0, stream>>>(mg, wpj, pjb, xout, xout,
                                                     MROWS, 1024, 4096);
}

// Round 3
// 1210.881 us; speedup vs baseline: 1.3307x; 1.3307x over previous
//
#include <hip/hip_runtime.h>
#include <hip/hip_bf16.h>

typedef __bf16 bf16x8 __attribute__((ext_vector_type(8)));
typedef __bf16 bf16x4 __attribute__((ext_vector_type(4)));
typedef float f32x4 __attribute__((ext_vector_type(4)));

#define SEQ 512
#define BATCH 32
#define DIM 1024
#define NHEAD 16
#define MROWS (SEQ * BATCH)   // 16384

__device__ __forceinline__ void gload16(const void* g, void* s) {
    __builtin_amdgcn_global_load_lds((const __attribute__((address_space(1))) void*)g,
                                     (__attribute__((address_space(3))) void*)s, 16, 0, 0);
}

__device__ __forceinline__ f32x4 mfma16(bf16x8 a, bf16x8 b, f32x4 c) {
    return __builtin_amdgcn_mfma_f32_16x16x32_bf16(a, b, c, 0, 0, 0);
}

// ---------------- f32 -> bf16 convert ----------------
__global__ __launch_bounds__(256) void cvt_kernel(const float* __restrict__ src,
                                                  __bf16* __restrict__ dst, int n) {
    int i = (blockIdx.x * 256 + threadIdx.x) * 4;
    if (i < n) {
        float4 v = *(const float4*)(src + i);
        bf16x4 o;
        o[0] = (__bf16)v.x; o[1] = (__bf16)v.y; o[2] = (__bf16)v.z; o[3] = (__bf16)v.w;
        *(bf16x4*)&dst[i] = o;
    }
}

// ---------------- LayerNorm (row of 1024) -> bf16 ----------------
__global__ __launch_bounds__(256) void ln_kernel(const float* __restrict__ x,
                                                 const float* __restrict__ w,
                                                 const float* __restrict__ b,
                                                 __bf16* __restrict__ out) {
    int row = blockIdx.x, t = threadIdx.x;
    const float4* xr = (const float4*)(x + (size_t)row * DIM);
    float4 v = xr[t];
    float s  = v.x + v.y + v.z + v.w;
    float ss = v.x * v.x + v.y * v.y + v.z * v.z + v.w * v.w;
#pragma unroll
    for (int o = 1; o < 64; o <<= 1) { s += __shfl_xor(s, o); ss += __shfl_xor(ss, o); }
    __shared__ float red[8];
    if ((t & 63) == 0) { red[t >> 6] = s; red[4 + (t >> 6)] = ss; }
    __syncthreads();
    s  = red[0] + red[1] + red[2] + red[3];
    ss = red[4] + red[5] + red[6] + red[7];
    float mu = s * (1.f / DIM);
    float rs = rsqrtf(ss * (1.f / DIM) - mu * mu + 1e-5f);
    int c = t * 4;
    bf16x4 o4;
    o4[0] = (__bf16)((v.x - mu) * rs * w[c + 0] + b[c + 0]);
    o4[1] = (__bf16)((v.y - mu) * rs * w[c + 1] + b[c + 1]);
    o4[2] = (__bf16)((v.z - mu) * rs * w[c + 2] + b[c + 2]);
    o4[3] = (__bf16)((v.w - mu) * rs * w[c + 3] + b[c + 3]);
    *(bf16x4*)&out[(size_t)row * DIM + c] = o4;
}

// ---------------- GEMM: out[M,N] = A[M,K] @ W[N,K]^T + bias (+act/+res) ----------------
// BK=64, XOR-swizzled LDS (pre-swizzled gload source), 128x128 tile, 4 waves.
// MODE 0: bf16 out;  1: bf16 out + quickGELU;  2: f32 out + residual
template <int MODE>
__global__ __launch_bounds__(256) void gemm_kernel(const __bf16* __restrict__ A,
                                                   const __bf16* __restrict__ W,
                                                   const float* __restrict__ bias,
                                                   const float* res, void* out,
                                                   int M, int N, int K) {
    __shared__ __bf16 As[128 * 64];
    __shared__ __bf16 Bs[128 * 64];
    char* Ab_s = (char*)As;
    char* Bb_s = (char*)Bs;
    int t = threadIdx.x, l = t & 63, wv = t >> 6;
    int m0 = blockIdx.y * 128, n0 = blockIdx.x * 128;
    int wm = (wv >> 1) * 64, wn = (wv & 1) * 64;
    int lr = l & 15, lqb = (l >> 4) * 16;   // lane row, lane k-byte
    f32x4 acc[4][4];
#pragma unroll
    for (int i = 0; i < 4; i++)
#pragma unroll
        for (int j = 0; j < 4; j++) acc[i][j] = (f32x4){0.f, 0.f, 0.f, 0.f};

    const __bf16* Ag = A + (size_t)m0 * K;
    const __bf16* Wg = W + (size_t)n0 * K;
    int srow = t >> 3, sslot = t & 7;       // staging: row within 32-row group, 16B slot

    for (int k0 = 0; k0 < K; k0 += 64) {
#pragma unroll
        for (int it = 0; it < 4; ++it) {
            int row = it * 32 + srow;
            int col = (sslot ^ (row & 7)) * 8;
            int L = it * 4096 + t * 16;
            gload16(Ag + (size_t)row * K + k0 + col, Ab_s + L);
            gload16(Wg + (size_t)row * K + k0 + col, Bb_s + L);
        }
        __syncthreads();
#pragma unroll
        for (int f2 = 0; f2 < 2; ++f2) {
            bf16x8 af[4], bfr[4];
#pragma unroll
            for (int i = 0; i < 4; i++) {
                int row = wm + i * 16 + lr;
                af[i] = *(const bf16x8*)(Ab_s + row * 128 + ((f2 * 64 + lqb) ^ ((row & 7) << 4)));
            }
#pragma unroll
            for (int j = 0; j < 4; j++) {
                int row = wn + j * 16 + lr;
                bfr[j] = *(const bf16x8*)(Bb_s + row * 128 + ((f2 * 64 + lqb) ^ ((row & 7) << 4)));
            }
#pragma unroll
            for (int i = 0; i < 4; i++)
#pragma unroll
                for (int j = 0; j < 4; j++)
                    acc[i][j] = mfma16(af[i], bfr[j], acc[i][j]);
        }
        __syncthreads();
    }

#pragma unroll
    for (int j = 0; j < 4; j++) {
        int col = n0 + wn + j * 16 + lr;
        float bv = bias[col];
#pragma unroll
        for (int i = 0; i < 4; i++) {
#pragma unroll
            for (int r = 0; r < 4; r++) {
                int row = m0 + wm + i * 16 + (l >> 4) * 4 + r;
                float v = acc[i][j][r] + bv;
                if (MODE == 1) v = v / (1.f + __expf(-1.702f * v));
                size_t idx = (size_t)row * N + col;
                if (MODE == 2) ((float*)out)[idx] = v + res[idx];
                else           ((__bf16*)out)[idx] = (__bf16)v;
            }
        }
    }
}

// ---------------- V transpose: qkv V-part (S,B,H,64) -> Vt (B,H,64,S) ----------------
// Block per (b,h,s-tile of 64). LDS tile [64][72-byte-stride] with s-dependent XOR swizzle.
__global__ __launch_bounds__(256) void vtr_kernel(const __bf16* __restrict__ qkv,
                                                  __bf16* __restrict__ Vt) {
    __shared__ __bf16 tl[64 * 72];
    char* tb = (char*)tl;
    int t = threadIdx.x;
    int bh = blockIdx.x >> 3, st = blockIdx.x & 7;
    int bb = bh >> 4, h = bh & 15;
#pragma unroll
    for (int it = 0; it < 2; ++it) {
        int s = it * 32 + (t >> 3), d0 = (t & 7) * 8;
        bf16x8 v = *(const bf16x8*)&qkv[((size_t)((st * 64 + s) * BATCH + bb)) * 3072 + 2048 + h * 64 + d0];
        *(bf16x8*)(tb + s * 144 + ((d0 * 2) ^ (((s + (s >> 3)) & 7) << 4))) = v;
    }
    __syncthreads();
#pragma unroll
    for (int it = 0; it < 2; ++it) {
        int d = it * 32 + (t >> 3), s0 = (t & 7) * 8;
        bf16x8 o;
#pragma unroll
        for (int e = 0; e < 8; ++e) {
            int s = s0 + e;
            o[e] = *(const __bf16*)(tb + s * 144 + ((d * 2) ^ (((s + (s >> 3)) & 7) << 4)));
        }
        *(bf16x8*)&Vt[((size_t)(bb * NHEAD + h) * 64 + d) * 512 + st * 64 + s0] = o;
    }
}

// ---------------- Fused attention v2 ----------------
// Block per (b, 32-row q-tile): 512 thr / 8 waves, 70 KB LDS -> 2 blocks/CU.
// K and Vt staged in 256-element halves into one 32KB union buffer via gload16
// with pre-swizzled source; register softmax; register mean-attn accumulator.
__global__ __launch_bounds__(512, 4) void attn_kernel(const __bf16* __restrict__ qkv,
                                                      const __bf16* __restrict__ Vt,
                                                      __bf16* __restrict__ ctx,
                                                      float* __restrict__ attnw) {
    __shared__ __bf16 kvbuf[16384];   // 32KB: K-half [256][64] swz  /  Vt-half [64][256] swz
    __shared__ __bf16 p16s[16384];    // 32KB: P [32][512] swz
    __shared__ __bf16 qts[2048];      //  4KB: Q [32][64] swz
    __shared__ float redm[32][4];
    __shared__ float reds[32][4];
    char* kvb = (char*)kvbuf;
    char* pps = (char*)p16s;
    char* qtb = (char*)qts;

    const int t = threadIdx.x;
    const int l = t & 63, w = t >> 6;
    const int wq = w >> 2, wc = w & 3;       // q-subtile (16 rows), col-slice
    const int lq = l >> 4, lr = l & 15;
    const int bb = blockIdx.x & 31;          // batch; same-b blocks land on same XCD
    const int qt0 = blockIdx.x >> 5;         // q-tile (32 rows)

    // staging decomposition
    const int ksl = t >> 3, kslot = t & 7;          // K: row-in-64-group, 16B slot
    const int vdl = t >> 5, vslot = t & 31;         // V: d-row-in-16-group, 16B slot

    float aw[8][4];
#pragma unroll
    for (int i = 0; i < 8; i++)
#pragma unroll
        for (int r = 0; r < 4; r++) aw[i][r] = 0.f;

    const int prow = wq * 16 + lr;           // P/Q A-frag row
    const int vd = wc * 16 + lr;             // Vt b-frag row (head-dim)

    for (int h = 0; h < NHEAD; ++h) {
        // ---- stage Q tile (first 4 waves) + K half 0 ----
        if (t < 256) {
            int qr = t >> 3, slot = t & 7;
            int d0 = (slot ^ (qr & 7)) * 8;
            gload16(qkv + ((size_t)((qt0 * 32 + qr) * BATCH + bb)) * 3072 + h * 64 + d0,
                    qtb + t * 16);
        }
#pragma unroll
        for (int it = 0; it < 4; ++it) {
            int s = it * 64 + ksl;
            int d0 = (kslot ^ (s & 7)) * 8;
            gload16(qkv + ((size_t)(s * BATCH + bb)) * 3072 + 1024 + h * 64 + d0,
                    kvb + it * 8192 + t * 16);
        }
        __syncthreads();                                            // (1)

        bf16x8 af0 = *(const bf16x8*)(qtb + prow * 128 + ((lq * 16) ^ ((prow & 7) << 4)));
        bf16x8 af1 = *(const bf16x8*)(qtb + prow * 128 + ((64 + lq * 16) ^ ((prow & 7) << 4)));

        f32x4 acc[8];
#pragma unroll
        for (int i = 0; i < 8; i++) acc[i] = (f32x4){0.f, 0.f, 0.f, 0.f};

#pragma unroll
        for (int ntl = 0; ntl < 4; ++ntl) {
            int r = wc * 64 + ntl * 16 + lr;
            bf16x8 b0 = *(const bf16x8*)(kvb + r * 128 + ((lq * 16) ^ ((r & 7) << 4)));
            bf16x8 b1 = *(const bf16x8*)(kvb + r * 128 + ((64 + lq * 16) ^ ((r & 7) << 4)));
            acc[ntl] = mfma16(af0, b0, acc[ntl]);
            acc[ntl] = mfma16(af1, b1, acc[ntl]);
        }
        __syncthreads();                                            // (2)
        // ---- stage K half 1 ----
#pragma unroll
        for (int it = 0; it < 4; ++it) {
            int s = it * 64 + ksl;
            int d0 = (kslot ^ (s & 7)) * 8;
            gload16(qkv + ((size_t)((256 + s) * BATCH + bb)) * 3072 + 1024 + h * 64 + d0,
                    kvb + it * 8192 + t * 16);
        }
        __syncthreads();                                            // (3)
#pragma unroll
        for (int ntl = 0; ntl < 4; ++ntl) {
            int r = wc * 64 + ntl * 16 + lr;
            bf16x8 b0 = *(const bf16x8*)(kvb + r * 128 + ((lq * 16) ^ ((r & 7) << 4)));
            bf16x8 b1 = *(const bf16x8*)(kvb + r * 128 + ((64 + lq * 16) ^ ((r & 7) << 4)));
            acc[4 + ntl] = mfma16(af0, b0, acc[4 + ntl]);
            acc[4 + ntl] = mfma16(af1, b1, acc[4 + ntl]);
        }
        __syncthreads();                                            // (4) K-buf free
        // ---- stage Vt half 0 (overlaps softmax) ----
#pragma unroll
        for (int it = 0; it < 4; ++it) {
            int d = it * 16 + vdl;
            int s0 = (vslot ^ (d & 7)) * 8;
            gload16(Vt + ((size_t)(bb * NHEAD + h) * 64 + d) * 512 + s0,
                    kvb + it * 8192 + t * 16);
        }
        // ---- softmax (registers + quarter shuffles + tiny LDS) ----
#pragma unroll
        for (int i = 0; i < 8; i++) acc[i] *= 0.125f;
        float mx[4];
#pragma unroll
        for (int r = 0; r < 4; ++r) {
            float m = acc[0][r];
#pragma unroll
            for (int i = 1; i < 8; ++i) m = fmaxf(m, acc[i][r]);
#pragma unroll
            for (int o = 1; o < 16; o <<= 1) m = fmaxf(m, __shfl_xor(m, o));
            mx[r] = m;
        }
        if (lr == 0) {
            redm[wq * 16 + lq * 4 + 0][wc] = mx[0];
            redm[wq * 16 + lq * 4 + 1][wc] = mx[1];
            redm[wq * 16 + lq * 4 + 2][wc] = mx[2];
            redm[wq * 16 + lq * 4 + 3][wc] = mx[3];
        }
        __syncthreads();                                            // (5)
        float g[4], sm[4];
#pragma unroll
        for (int r = 0; r < 4; ++r) {
            int row = wq * 16 + lq * 4 + r;
            g[r] = fmaxf(fmaxf(redm[row][0], redm[row][1]),
                         fmaxf(redm[row][2], redm[row][3]));
            sm[r] = 0.f;
        }
#pragma unroll
        for (int i = 0; i < 8; ++i)
#pragma unroll
            for (int r = 0; r < 4; ++r) {
                float p = __expf(acc[i][r] - g[r]);
                acc[i][r] = p;
                sm[r] += p;
            }
#pragma unroll
        for (int r = 0; r < 4; ++r)
#pragma unroll
            for (int o = 1; o < 16; o <<= 1) sm[r] += __shfl_xor(sm[r], o);
        if (lr == 0) {
            reds[wq * 16 + lq * 4 + 0][wc] = sm[0];
            reds[wq * 16 + lq * 4 + 1][wc] = sm[1];
            reds[wq * 16 + lq * 4 + 2][wc] = sm[2];
            reds[wq * 16 + lq * 4 + 3][wc] = sm[3];
        }
        __syncthreads();                                            // (6)
        float inv[4];
#pragma unroll
        for (int r = 0; r < 4; ++r) {
            int row = wq * 16 + lq * 4 + r;
            inv[r] = 1.f / (reds[row][0] + reds[row][1] + reds[row][2] + reds[row][3]);
        }
        // ---- write P (bf16, swizzled) + accumulate mean-attn in registers ----
#pragma unroll
        for (int i = 0; i < 8; ++i) {
#pragma unroll
            for (int r = 0; r < 4; ++r) {
                float pn = acc[i][r] * inv[r];
                aw[i][r] += pn;
                int row = wq * 16 + lq * 4 + r;
                int cbyte = (i >> 2) * 512 + wc * 128 + (i & 3) * 32 + lr * 2;
                *(__bf16*)(pps + row * 1024 + (cbyte ^ ((row & 7) << 4))) = (__bf16)pn;
            }
        }
        __syncthreads();                                            // (7) P + V0 ready
        // ---- PV half 0 ----
        f32x4 cacc = (f32x4){0.f, 0.f, 0.f, 0.f};
#pragma unroll
        for (int ks = 0; ks < 8; ++ks) {
            bf16x8 ap = *(const bf16x8*)(pps + prow * 1024 + ((ks * 64 + lq * 16) ^ ((prow & 7) << 4)));
            bf16x8 bv = *(const bf16x8*)(kvb + vd * 512 + ((ks * 64 + lq * 16) ^ ((vd & 7) << 4)));
            cacc = mfma16(ap, bv, cacc);
        }
        __syncthreads();                                            // (8) V-buf free
        // ---- stage Vt half 1 ----
#pragma unroll
        for (int it = 0; it < 4; ++it) {
            int d = it * 16 + vdl;
            int s0 = (vslot ^ (d & 7)) * 8;
            gload16(Vt + ((size_t)(bb * NHEAD + h) * 64 + d) * 512 + 256 + s0,
                    kvb + it * 8192 + t * 16);
        }
        __syncthreads();                                            // (9)
#pragma unroll
        for (int ks = 0; ks < 8; ++ks) {
            bf16x8 ap = *(const bf16x8*)(pps + prow * 1024 + ((512 + ks * 64 + lq * 16) ^ ((prow & 7) << 4)));
            bf16x8 bv = *(const bf16x8*)(kvb + vd * 512 + ((ks * 64 + lq * 16) ^ ((vd & 7) << 4)));
            cacc = mfma16(ap, bv, cacc);
        }
        // ---- write ctx slice ----
#pragma unroll
        for (int r = 0; r < 4; ++r) {
            int q = qt0 * 32 + wq * 16 + lq * 4 + r;
            ctx[((size_t)(q * BATCH + bb)) * DIM + h * 64 + wc * 16 + lr] = (__bf16)cacc[r];
        }
        __syncthreads();                                            // (10)
    }
    // ---- write mean attention weights ----
#pragma unroll
    for (int i = 0; i < 8; ++i)
#pragma unroll
        for (int r = 0; r < 4; ++r) {
            int q = qt0 * 32 + wq * 16 + lq * 4 + r;
            int col = (i >> 2) * 256 + wc * 64 + (i & 3) * 16 + lr;
            attnw[(size_t)bb * (SEQ * SEQ) + (size_t)q * SEQ + col] = aw[i][r] * (1.f / NHEAD);
        }
}

// ---------------- launch ----------------
extern "C" void kernel_launch(void* const* d_in, const int* in_sizes, int n_in,
                              void* d_out, int out_size, void* d_ws, size_t ws_size,
                              hipStream_t stream) {
    const float* x    = (const float*)d_in[0];
    const float* ln1w = (const float*)d_in[1];
    const float* ln1b = (const float*)d_in[2];
    const float* ipw  = (const float*)d_in[3];
    const float* ipb  = (const float*)d_in[4];
    const float* outw = (const float*)d_in[5];
    const float* outb = (const float*)d_in[6];
    const float* ln2w = (const float*)d_in[7];
    const float* ln2b = (const float*)d_in[8];
    const float* fcw  = (const float*)d_in[9];
    const float* fcb  = (const float*)d_in[10];
    const float* pjw  = (const float*)d_in[11];
    const float* pjb  = (const float*)d_in[12];

    float* xout  = (float*)d_out;                       // (S,B,D) final
    float* awout = xout + (size_t)MROWS * DIM;          // (B,S,S)

    // workspace layout (bf16 elems)
    __bf16* wip   = (__bf16*)d_ws;                      // 3072x1024
    __bf16* wout_ = wip + 3145728;                      // 1024x1024
    __bf16* wfc   = wout_ + 1048576;                    // 4096x1024
    __bf16* wpj   = wfc + 4194304;                      // 1024x4096
    __bf16* hbuf  = wpj + 4194304;                      // 16384x1024 (ln out / Vt alias)
    __bf16* big   = hbuf + (size_t)MROWS * DIM;
    __bf16* qkv   = big;                                // 16384x3072
    __bf16* ctxb  = big + (size_t)MROWS * 3072;         // 16384x1024
    __bf16* mg    = big;                                // 16384x4096 (aliases qkv+ctx later)
    __bf16* Vt    = hbuf;                               // (B,H,64,S) = 16777216 elems, aliases hbuf

    cvt_kernel<<<3072, 256, 0, stream>>>(ipw,  wip,   3145728);
    cvt_kernel<<<1024, 256, 0, stream>>>(outw, wout_, 1048576);
    cvt_kernel<<<4096, 256, 0, stream>>>(fcw,  wfc,   4194304);
    cvt_kernel<<<4096, 256, 0, stream>>>(pjw,  wpj,   4194304);

    ln_kernel<<<MROWS, 256, 0, stream>>>(x, ln1w, ln1b, hbuf);

    gemm_kernel<0><<<dim3(24, 128), 256, 0, stream>>>(hbuf, wip, ipb, nullptr, qkv,
                                                      MROWS, 3072, 1024);

    vtr_kernel<<<32 * 16 * 8, 256, 0, stream>>>(qkv, Vt);   // hbuf now dead -> Vt

    attn_kernel<<<512, 512, 0, stream>>>(qkv, Vt, ctxb, awout);

    gemm_kernel<2><<<dim3(8, 128), 256, 0, stream>>>(ctxb, wout_, outb, x, xout,
                                                     MROWS, 1024, 1024);

    ln_kernel<<<MROWS, 256, 0, stream>>>(xout, ln2w, ln2b, hbuf);

    gemm_kernel<1><<<dim3(32, 128), 256, 0, stream>>>(hbuf, wfc, fcb, nullptr, mg,
                                                      MROWS, 4096, 1024);

    gemm_kernel<2><<<dim3(8, 128), 256, 0, stream>>>(mg, wpj, pjb, xout, xout,
                                                     MROWS, 1024, 4096);
}

// Round 5
// 1106.762 us; speedup vs baseline: 1.4559x; 1.0941x over previous
//
#include <hip/hip_runtime.h>
#include <hip/hip_bf16.h>

typedef __bf16 bf16x8 __attribute__((ext_vector_type(8)));
typedef __bf16 bf16x4 __attribute__((ext_vector_type(4)));
typedef float f32x4 __attribute__((ext_vector_type(4)));

#define SEQ 512
#define BATCH 32
#define DIM 1024
#define NHEAD 16
#define MROWS (SEQ * BATCH)   // 16384

__device__ __forceinline__ void gload16(const void* g, void* s) {
    __builtin_amdgcn_global_load_lds((const __attribute__((address_space(1))) void*)g,
                                     (__attribute__((address_space(3))) void*)s, 16, 0, 0);
}

__device__ __forceinline__ f32x4 mfma16(bf16x8 a, bf16x8 b, f32x4 c) {
    return __builtin_amdgcn_mfma_f32_16x16x32_bf16(a, b, c, 0, 0, 0);
}

// ---------------- f32 -> bf16 convert ----------------
__global__ __launch_bounds__(256) void cvt_kernel(const float* __restrict__ src,
                                                  __bf16* __restrict__ dst, int n) {
    int i = (blockIdx.x * 256 + threadIdx.x) * 4;
    if (i < n) {
        float4 v = *(const float4*)(src + i);
        bf16x4 o;
        o[0] = (__bf16)v.x; o[1] = (__bf16)v.y; o[2] = (__bf16)v.z; o[3] = (__bf16)v.w;
        *(bf16x4*)&dst[i] = o;
    }
}

// ---------------- LayerNorm (row of 1024) -> bf16 ----------------
__global__ __launch_bounds__(256) void ln_kernel(const float* __restrict__ x,
                                                 const float* __restrict__ w,
                                                 const float* __restrict__ b,
                                                 __bf16* __restrict__ out) {
    int row = blockIdx.x, t = threadIdx.x;
    const float4* xr = (const float4*)(x + (size_t)row * DIM);
    float4 v = xr[t];
    float s  = v.x + v.y + v.z + v.w;
    float ss = v.x * v.x + v.y * v.y + v.z * v.z + v.w * v.w;
#pragma unroll
    for (int o = 1; o < 64; o <<= 1) { s += __shfl_xor(s, o); ss += __shfl_xor(ss, o); }
    __shared__ float red[8];
    if ((t & 63) == 0) { red[t >> 6] = s; red[4 + (t >> 6)] = ss; }
    __syncthreads();
    s  = red[0] + red[1] + red[2] + red[3];
    ss = red[4] + red[5] + red[6] + red[7];
    float mu = s * (1.f / DIM);
    float rs = rsqrtf(ss * (1.f / DIM) - mu * mu + 1e-5f);
    int c = t * 4;
    bf16x4 o4;
    o4[0] = (__bf16)((v.x - mu) * rs * w[c + 0] + b[c + 0]);
    o4[1] = (__bf16)((v.y - mu) * rs * w[c + 1] + b[c + 1]);
    o4[2] = (__bf16)((v.z - mu) * rs * w[c + 2] + b[c + 2]);
    o4[3] = (__bf16)((v.w - mu) * rs * w[c + 3] + b[c + 3]);
    *(bf16x4*)&out[(size_t)row * DIM + c] = o4;
}

// ---------------- 8-phase 256x256 GEMM: out[M,N] = A[M,K] @ W[N,K]^T + bias ----------------
// T1 XCD swizzle + T2 LDS swizzle + T3/T4 8-phase counted vmcnt + T5 setprio.
// 8 waves (2M x 4N), BK=64, 128KB LDS double-buffer, gload_lds w/ pre-swizzled source.
// MODE 0: bf16 out;  1: bf16 out + quickGELU;  2: f32 out + residual
#define BA0 0
#define BB0 32768
#define BA1 65536
#define BB1 98304

#define PH_MID \
    __builtin_amdgcn_s_barrier(); \
    asm volatile("s_waitcnt lgkmcnt(0)" ::: "memory"); \
    __builtin_amdgcn_sched_barrier(0); \
    __builtin_amdgcn_s_setprio(1);
#define PH_END \
    __builtin_amdgcn_s_setprio(0); \
    __builtin_amdgcn_sched_barrier(0); \
    __builtin_amdgcn_s_barrier();
#define PH_END_VM4 \
    __builtin_amdgcn_s_setprio(0); \
    __builtin_amdgcn_sched_barrier(0); \
    asm volatile("s_waitcnt vmcnt(4)" ::: "memory"); \
    __builtin_amdgcn_s_barrier();
#define PH_END_VM0 \
    __builtin_amdgcn_s_setprio(0); \
    __builtin_amdgcn_sched_barrier(0); \
    asm volatile("s_waitcnt vmcnt(0)" ::: "memory"); \
    __builtin_amdgcn_s_barrier();

template <int MODE>
__global__ __launch_bounds__(512, 2) void gemm8_kernel(const __bf16* __restrict__ A,
                                                       const __bf16* __restrict__ W,
                                                       const float* __restrict__ bias,
                                                       const float* res, void* out,
                                                       int M, int N, int K) {
    __shared__ __align__(16) char lds[131072];
    const int t = threadIdx.x, l = t & 63, wid = t >> 6;
    const int wm = wid >> 2, wn = wid & 3;          // 2 x 4 wave grid
    const int lr = l & 15, lq = l >> 4;
    const int kx = (lr & 7) << 4;                   // lane swizzle key (row&7 == lr&7)

    // XCD-aware block swizzle (nwg % 8 == 0 for all our shapes)
    const int nwg = gridDim.x;
    const int cpx = nwg >> 3;
    const int swz = ((int)blockIdx.x & 7) * cpx + ((int)blockIdx.x >> 3);
    const int MT = M >> 8;
    const int nt = swz / MT, mt = swz - nt * MT;    // mt-inner: consecutive share B panel
    const __bf16* Ag = A + ((size_t)mt << 8) * K;
    const __bf16* Wg = W + ((size_t)nt << 8) * K;
    const int NITER = K >> 7;                       // 2 K-tiles (BK=64) per iteration

    // stage one half-tile (128 rows x 64 k) into lds[dstbase..+16KB), linear dest,
    // inverse-swizzled global source (G21).
    auto STAGE = [&](int dstbase, const __bf16* src, int half, int kt) {
#pragma unroll
        for (int i = 0; i < 2; ++i) {
            int idx = i * 512 + t;
            int r = idx >> 3, slot = idx & 7;
            gload16(src + (size_t)(half * 128 + r) * K + kt * 64 + ((slot ^ (r & 7)) << 3),
                    lds + dstbase + idx * 16);
        }
    };
    auto LDA_ = [&](int base, int mi, int ks) -> bf16x8 {
        int row = wm * 128 + mi * 16 + lr;
        return *(const bf16x8*)(lds + base + row * 128 + ((ks * 64 + lq * 16) ^ kx));
    };
    auto LDB_ = [&](int base, int nj, int ks) -> bf16x8 {
        int row = wn * 64 + nj * 16 + lr;
        return *(const bf16x8*)(lds + base + row * 128 + ((ks * 64 + lq * 16) ^ kx));
    };

    f32x4 acc[8][4];
#pragma unroll
    for (int i = 0; i < 8; ++i)
#pragma unroll
        for (int j = 0; j < 4; ++j) acc[i][j] = (f32x4){0.f, 0.f, 0.f, 0.f};

    // ---- prologue: kt0 {B0,B1,A0,A1}, kt1 {B0,B1}; kt1 {A0,A1} staged in P1/P2 ----
    STAGE(BB0, Wg, 0, 0); STAGE(BB0 + 16384, Wg, 1, 0);
    STAGE(BA0, Ag, 0, 0); STAGE(BA0 + 16384, Ag, 1, 0);
    STAGE(BB1, Wg, 0, 1); STAGE(BB1 + 16384, Wg, 1, 1);
    asm volatile("s_waitcnt vmcnt(4)" ::: "memory");   // kt0 fully landed
    __builtin_amdgcn_s_barrier();

    for (int ki = 0; ki < NITER; ++ki) {
        const int ks1 = 2 * ki + 1, ks2 = 2 * ki + 2, ks3 = 2 * ki + 3;
        const bool st23 = (ki + 1 < NITER);
        bf16x8 af[4][2], bfr[4][2];

        // ---- P1: A(buf0) mi0-3 + B(buf0) nj0-1; stage kt1.A0 -> buf1 ----
        __builtin_amdgcn_sched_barrier(0);
#pragma unroll
        for (int mi = 0; mi < 4; ++mi) { af[mi][0] = LDA_(BA0, mi, 0); af[mi][1] = LDA_(BA0, mi, 1); }
#pragma unroll
        for (int nj = 0; nj < 2; ++nj) { bfr[nj][0] = LDB_(BB0, nj, 0); bfr[nj][1] = LDB_(BB0, nj, 1); }
        STAGE(BA1, Ag, 0, ks1);
        PH_MID
#pragma unroll
        for (int mi = 0; mi < 4; ++mi)
#pragma unroll
            for (int nj = 0; nj < 2; ++nj) {
                acc[mi][nj] = mfma16(af[mi][0], bfr[nj][0], acc[mi][nj]);
                acc[mi][nj] = mfma16(af[mi][1], bfr[nj][1], acc[mi][nj]);
            }
        PH_END

        // ---- P2: B nj2-3; stage kt1.A1 ----
        __builtin_amdgcn_sched_barrier(0);
#pragma unroll
        for (int nj = 2; nj < 4; ++nj) { bfr[nj][0] = LDB_(BB0, nj, 0); bfr[nj][1] = LDB_(BB0, nj, 1); }
        STAGE(BA1 + 16384, Ag, 1, ks1);
        PH_MID
#pragma unroll
        for (int mi = 0; mi < 4; ++mi)
#pragma unroll
            for (int nj = 2; nj < 4; ++nj) {
                acc[mi][nj] = mfma16(af[mi][0], bfr[nj][0], acc[mi][nj]);
                acc[mi][nj] = mfma16(af[mi][1], bfr[nj][1], acc[mi][nj]);
            }
        PH_END

        // ---- P3: A mi4-7; stage kt2.B0 -> buf0 (buf0.B last read at P2) ----
        __builtin_amdgcn_sched_barrier(0);
#pragma unroll
        for (int m = 0; m < 4; ++m) { af[m][0] = LDA_(BA0, m + 4, 0); af[m][1] = LDA_(BA0, m + 4, 1); }
        if (st23) STAGE(BB0, Wg, 0, ks2);
        PH_MID
#pragma unroll
        for (int m = 0; m < 4; ++m)
#pragma unroll
            for (int nj = 0; nj < 2; ++nj) {
                acc[m + 4][nj] = mfma16(af[m][0], bfr[nj][0], acc[m + 4][nj]);
                acc[m + 4][nj] = mfma16(af[m][1], bfr[nj][1], acc[m + 4][nj]);
            }
        PH_END

        // ---- P4: stage kt2.B1; vmcnt gates kt1.A0/A1 for P5 ----
        __builtin_amdgcn_sched_barrier(0);
        if (st23) STAGE(BB0 + 16384, Wg, 1, ks2);
        PH_MID
#pragma unroll
        for (int m = 0; m < 4; ++m)
#pragma unroll
            for (int nj = 2; nj < 4; ++nj) {
                acc[m + 4][nj] = mfma16(af[m][0], bfr[nj][0], acc[m + 4][nj]);
                acc[m + 4][nj] = mfma16(af[m][1], bfr[nj][1], acc[m + 4][nj]);
            }
        if (st23) { PH_END_VM4 } else { PH_END_VM0 }

        // ---- P5: A(buf1) mi0-3 + B(buf1) nj0-1; stage kt2.A0 -> buf0 (A last read P3) ----
        __builtin_amdgcn_sched_barrier(0);
#pragma unroll
        for (int mi = 0; mi < 4; ++mi) { af[mi][0] = LDA_(BA1, mi, 0); af[mi][1] = LDA_(BA1, mi, 1); }
#pragma unroll
        for (int nj = 0; nj < 2; ++nj) { bfr[nj][0] = LDB_(BB1, nj, 0); bfr[nj][1] = LDB_(BB1, nj, 1); }
        if (st23) STAGE(BA0, Ag, 0, ks2);
        PH_MID
#pragma unroll
        for (int mi = 0; mi < 4; ++mi)
#pragma unroll
            for (int nj = 0; nj < 2; ++nj) {
                acc[mi][nj] = mfma16(af[mi][0], bfr[nj][0], acc[mi][nj]);
                acc[mi][nj] = mfma16(af[mi][1], bfr[nj][1], acc[mi][nj]);
            }
        PH_END

        // ---- P6: B nj2-3; stage kt2.A1 ----
        __builtin_amdgcn_sched_barrier(0);
#pragma unroll
        for (int nj = 2; nj < 4; ++nj) { bfr[nj][0] = LDB_(BB1, nj, 0); bfr[nj][1] = LDB_(BB1, nj, 1); }
        if (st23) STAGE(BA0 + 16384, Ag, 1, ks2);
        PH_MID
#pragma unroll
        for (int mi = 0; mi < 4; ++mi)
#pragma unroll
            for (int nj = 2; nj < 4; ++nj) {
                acc[mi][nj] = mfma16(af[mi][0], bfr[nj][0], acc[mi][nj]);
                acc[mi][nj] = mfma16(af[mi][1], bfr[nj][1], acc[mi][nj]);
            }
        PH_END

        // ---- P7: A mi4-7; stage kt3.B0 -> buf1 (buf1.B last read P6) ----
        __builtin_amdgcn_sched_barrier(0);
#pragma unroll
        for (int m = 0; m < 4; ++m) { af[m][0] = LDA_(BA1, m + 4, 0); af[m][1] = LDA_(BA1, m + 4, 1); }
        if (st23) STAGE(BB1, Wg, 0, ks3);
        PH_MID
#pragma unroll
        for (int m = 0; m < 4; ++m)
#pragma unroll
            for (int nj = 0; nj < 2; ++nj) {
                acc[m + 4][nj] = mfma16(af[m][0], bfr[nj][0], acc[m + 4][nj]);
                acc[m + 4][nj] = mfma16(af[m][1], bfr[nj][1], acc[m + 4][nj]);
            }
        PH_END

        // ---- P8: stage kt3.B1; vmcnt gates kt2 for next P1 ----
        __builtin_amdgcn_sched_barrier(0);
        if (st23) STAGE(BB1 + 16384, Wg, 1, ks3);
        PH_MID
#pragma unroll
        for (int m = 0; m < 4; ++m)
#pragma unroll
            for (int nj = 2; nj < 4; ++nj) {
                acc[m + 4][nj] = mfma16(af[m][0], bfr[nj][0], acc[m + 4][nj]);
                acc[m + 4][nj] = mfma16(af[m][1], bfr[nj][1], acc[m + 4][nj]);
            }
        PH_END_VM4
    }

    // ---- epilogue ----
#pragma unroll
    for (int nj = 0; nj < 4; ++nj) {
        int col = (nt << 8) + wn * 64 + nj * 16 + lr;
        float bv = bias[col];
#pragma unroll
        for (int mi = 0; mi < 8; ++mi) {
#pragma unroll
            for (int r = 0; r < 4; ++r) {
                int row = (mt << 8) + wm * 128 + mi * 16 + lq * 4 + r;
                float v = acc[mi][nj][r] + bv;
                if (MODE == 1) v = v / (1.f + __expf(-1.702f * v));
                size_t idx = (size_t)row * N + col;
                if (MODE == 2) ((float*)out)[idx] = v + res[idx];
                else           ((__bf16*)out)[idx] = (__bf16)v;
            }
        }
    }
}

// ---------------- V transpose: qkv V-part (S,B,H,64) -> Vt (B,H,64,S) ----------------
__global__ __launch_bounds__(256) void vtr_kernel(const __bf16* __restrict__ qkv,
                                                  __bf16* __restrict__ Vt) {
    __shared__ __bf16 tl[64 * 72];
    char* tb = (char*)tl;
    int t = threadIdx.x;
    int bh = blockIdx.x >> 3, st = blockIdx.x & 7;
    int bb = bh >> 4, h = bh & 15;
#pragma unroll
    for (int it = 0; it < 2; ++it) {
        int s = it * 32 + (t >> 3), d0 = (t & 7) * 8;
        bf16x8 v = *(const bf16x8*)&qkv[((size_t)((st * 64 + s) * BATCH + bb)) * 3072 + 2048 + h * 64 + d0];
        *(bf16x8*)(tb + s * 144 + ((d0 * 2) ^ (((s + (s >> 3)) & 7) << 4))) = v;
    }
    __syncthreads();
#pragma unroll
    for (int it = 0; it < 2; ++it) {
        int d = it * 32 + (t >> 3), s0 = (t & 7) * 8;
        bf16x8 o;
#pragma unroll
        for (int e = 0; e < 8; ++e) {
            int s = s0 + e;
            o[e] = *(const __bf16*)(tb + s * 144 + ((d * 2) ^ (((s + (s >> 3)) & 7) << 4)));
        }
        *(bf16x8*)&Vt[((size_t)(bb * NHEAD + h) * 64 + d) * 512 + st * 64 + s0] = o;
    }
}

// ---------------- Fused attention (unchanged from round 3) ----------------
__global__ __launch_bounds__(512, 4) void attn_kernel(const __bf16* __restrict__ qkv,
                                                      const __bf16* __restrict__ Vt,
                                                      __bf16* __restrict__ ctx,
                                                      float* __restrict__ attnw) {
    __shared__ __bf16 kvbuf[16384];
    __shared__ __bf16 p16s[16384];
    __shared__ __bf16 qts[2048];
    __shared__ float redm[32][4];
    __shared__ float reds[32][4];
    char* kvb = (char*)kvbuf;
    char* pps = (char*)p16s;
    char* qtb = (char*)qts;

    const int t = threadIdx.x;
    const int l = t & 63, w = t >> 6;
    const int wq = w >> 2, wc = w & 3;
    const int lq = l >> 4, lr = l & 15;
    const int bb = blockIdx.x & 31;
    const int qt0 = blockIdx.x >> 5;

    const int ksl = t >> 3, kslot = t & 7;
    const int vdl = t >> 5, vslot = t & 31;

    float aw[8][4];
#pragma unroll
    for (int i = 0; i < 8; i++)
#pragma unroll
        for (int r = 0; r < 4; r++) aw[i][r] = 0.f;

    const int prow = wq * 16 + lr;
    const int vd = wc * 16 + lr;

    for (int h = 0; h < NHEAD; ++h) {
        if (t < 256) {
            int qr = t >> 3, slot = t & 7;
            int d0 = (slot ^ (qr & 7)) * 8;
            gload16(qkv + ((size_t)((qt0 * 32 + qr) * BATCH + bb)) * 3072 + h * 64 + d0,
                    qtb + t * 16);
        }
#pragma unroll
        for (int it = 0; it < 4; ++it) {
            int s = it * 64 + ksl;
            int d0 = (kslot ^ (s & 7)) * 8;
            gload16(qkv + ((size_t)(s * BATCH + bb)) * 3072 + 1024 + h * 64 + d0,
                    kvb + it * 8192 + t * 16);
        }
        __syncthreads();

        bf16x8 af0 = *(const bf16x8*)(qtb + prow * 128 + ((lq * 16) ^ ((prow & 7) << 4)));
        bf16x8 af1 = *(const bf16x8*)(qtb + prow * 128 + ((64 + lq * 16) ^ ((prow & 7) << 4)));

        f32x4 acc[8];
#pragma unroll
        for (int i = 0; i < 8; i++) acc[i] = (f32x4){0.f, 0.f, 0.f, 0.f};

#pragma unroll
        for (int ntl = 0; ntl < 4; ++ntl) {
            int r = wc * 64 + ntl * 16 + lr;
            bf16x8 b0 = *(const bf16x8*)(kvb + r * 128 + ((lq * 16) ^ ((r & 7) << 4)));
            bf16x8 b1 = *(const bf16x8*)(kvb + r * 128 + ((64 + lq * 16) ^ ((r & 7) << 4)));
            acc[ntl] = mfma16(af0, b0, acc[ntl]);
            acc[ntl] = mfma16(af1, b1, acc[ntl]);
        }
        __syncthreads();
#pragma unroll
        for (int it = 0; it < 4; ++it) {
            int s = it * 64 + ksl;
            int d0 = (kslot ^ (s & 7)) * 8;
            gload16(qkv + ((size_t)((256 + s) * BATCH + bb)) * 3072 + 1024 + h * 64 + d0,
                    kvb + it * 8192 + t * 16);
        }
        __syncthreads();
#pragma unroll
        for (int ntl = 0; ntl < 4; ++ntl) {
            int r = wc * 64 + ntl * 16 + lr;
            bf16x8 b0 = *(const bf16x8*)(kvb + r * 128 + ((lq * 16) ^ ((r & 7) << 4)));
            bf16x8 b1 = *(const bf16x8*)(kvb + r * 128 + ((64 + lq * 16) ^ ((r & 7) << 4)));
            acc[4 + ntl] = mfma16(af0, b0, acc[4 + ntl]);
            acc[4 + ntl] = mfma16(af1, b1, acc[4 + ntl]);
        }
        __syncthreads();
#pragma unroll
        for (int it = 0; it < 4; ++it) {
            int d = it * 16 + vdl;
            int s0 = (vslot ^ (d & 7)) * 8;
            gload16(Vt + ((size_t)(bb * NHEAD + h) * 64 + d) * 512 + s0,
                    kvb + it * 8192 + t * 16);
        }
#pragma unroll
        for (int i = 0; i < 8; i++) acc[i] *= 0.125f;
        float mx[4];
#pragma unroll
        for (int r = 0; r < 4; ++r) {
            float m = acc[0][r];
#pragma unroll
            for (int i = 1; i < 8; ++i) m = fmaxf(m, acc[i][r]);
#pragma unroll
            for (int o = 1; o < 16; o <<= 1) m = fmaxf(m, __shfl_xor(m, o));
            mx[r] = m;
        }
        if (lr == 0) {
            redm[wq * 16 + lq * 4 + 0][wc] = mx[0];
            redm[wq * 16 + lq * 4 + 1][wc] = mx[1];
            redm[wq * 16 + lq * 4 + 2][wc] = mx[2];
            redm[wq * 16 + lq * 4 + 3][wc] = mx[3];
        }
        __syncthreads();
        float g[4], sm[4];
#pragma unroll
        for (int r = 0; r < 4; ++r) {
            int row = wq * 16 + lq * 4 + r;
            g[r] = fmaxf(fmaxf(redm[row][0], redm[row][1]),
                         fmaxf(redm[row][2], redm[row][3]));
            sm[r] = 0.f;
        }
#pragma unroll
        for (int i = 0; i < 8; ++i)
#pragma unroll
            for (int r = 0; r < 4; ++r) {
                float p = __expf(acc[i][r] - g[r]);
                acc[i][r] = p;
                sm[r] += p;
            }
#pragma unroll
        for (int r = 0; r < 4; ++r)
#pragma unroll
            for (int o = 1; o < 16; o <<= 1) sm[r] += __shfl_xor(sm[r], o);
        if (lr == 0) {
            reds[wq * 16 + lq * 4 + 0][wc] = sm[0];
            reds[wq * 16 + lq * 4 + 1][wc] = sm[1];
            reds[wq * 16 + lq * 4 + 2][wc] = sm[2];
            reds[wq * 16 + lq * 4 + 3][wc] = sm[3];
        }
        __syncthreads();
        float inv[4];
#pragma unroll
        for (int r = 0; r < 4; ++r) {
            int row = wq * 16 + lq * 4 + r;
            inv[r] = 1.f / (reds[row][0] + reds[row][1] + reds[row][2] + reds[row][3]);
        }
#pragma unroll
        for (int i = 0; i < 8; ++i) {
#pragma unroll
            for (int r = 0; r < 4; ++r) {
                float pn = acc[i][r] * inv[r];
                aw[i][r] += pn;
                int row = wq * 16 + lq * 4 + r;
                int cbyte = (i >> 2) * 512 + wc * 128 + (i & 3) * 32 + lr * 2;
                *(__bf16*)(pps + row * 1024 + (cbyte ^ ((row & 7) << 4))) = (__bf16)pn;
            }
        }
        __syncthreads();
        f32x4 cacc = (f32x4){0.f, 0.f, 0.f, 0.f};
#pragma unroll
        for (int ks = 0; ks < 8; ++ks) {
            bf16x8 ap = *(const bf16x8*)(pps + prow * 1024 + ((ks * 64 + lq * 16) ^ ((prow & 7) << 4)));
            bf16x8 bv = *(const bf16x8*)(kvb + vd * 512 + ((ks * 64 + lq * 16) ^ ((vd & 7) << 4)));
            cacc = mfma16(ap, bv, cacc);
        }
        __syncthreads();
#pragma unroll
        for (int it = 0; it < 4; ++it) {
            int d = it * 16 + vdl;
            int s0 = (vslot ^ (d & 7)) * 8;
            gload16(Vt + ((size_t)(bb * NHEAD + h) * 64 + d) * 512 + 256 + s0,
                    kvb + it * 8192 + t * 16);
        }
        __syncthreads();
#pragma unroll
        for (int ks = 0; ks < 8; ++ks) {
            bf16x8 ap = *(const bf16x8*)(pps + prow * 1024 + ((512 + ks * 64 + lq * 16) ^ ((prow & 7) << 4)));
            bf16x8 bv = *(const bf16x8*)(kvb + vd * 512 + ((ks * 64 + lq * 16) ^ ((vd & 7) << 4)));
            cacc = mfma16(ap, bv, cacc);
        }
#pragma unroll
        for (int r = 0; r < 4; ++r) {
            int q = qt0 * 32 + wq * 16 + lq * 4 + r;
            ctx[((size_t)(q * BATCH + bb)) * DIM + h * 64 + wc * 16 + lr] = (__bf16)cacc[r];
        }
        __syncthreads();
    }
#pragma unroll
    for (int i = 0; i < 8; ++i)
#pragma unroll
        for (int r = 0; r < 4; ++r) {
            int q = qt0 * 32 + wq * 16 + lq * 4 + r;
            int col = (i >> 2) * 256 + wc * 64 + (i & 3) * 16 + lr;
            attnw[(size_t)bb * (SEQ * SEQ) + (size_t)q * SEQ + col] = aw[i][r] * (1.f / NHEAD);
        }
}

// ---------------- launch ----------------
extern "C" void kernel_launch(void* const* d_in, const int* in_sizes, int n_in,
                              void* d_out, int out_size, void* d_ws, size_t ws_size,
                              hipStream_t stream) {
    const float* x    = (const float*)d_in[0];
    const float* ln1w = (const float*)d_in[1];
    const float* ln1b = (const float*)d_in[2];
    const float* ipw  = (const float*)d_in[3];
    const float* ipb  = (const float*)d_in[4];
    const float* outw = (const float*)d_in[5];
    const float* outb = (const float*)d_in[6];
    const float* ln2w = (const float*)d_in[7];
    const float* ln2b = (const float*)d_in[8];
    const float* fcw  = (const float*)d_in[9];
    const float* fcb  = (const float*)d_in[10];
    const float* pjw  = (const float*)d_in[11];
    const float* pjb  = (const float*)d_in[12];

    float* xout  = (float*)d_out;                       // (S,B,D) final
    float* awout = xout + (size_t)MROWS * DIM;          // (B,S,S)

    __bf16* wip   = (__bf16*)d_ws;                      // 3072x1024
    __bf16* wout_ = wip + 3145728;                      // 1024x1024
    __bf16* wfc   = wout_ + 1048576;                    // 4096x1024
    __bf16* wpj   = wfc + 4194304;                      // 1024x4096
    __bf16* hbuf  = wpj + 4194304;                      // 16384x1024 (ln out / Vt alias)
    __bf16* big   = hbuf + (size_t)MROWS * DIM;
    __bf16* qkv   = big;                                // 16384x3072
    __bf16* ctxb  = big + (size_t)MROWS * 3072;         // 16384x1024
    __bf16* mg    = big;                                // 16384x4096 (aliases qkv+ctx later)
    __bf16* Vt    = hbuf;                               // (B,H,64,S), aliases hbuf

    cvt_kernel<<<3072, 256, 0, stream>>>(ipw,  wip,   3145728);
    cvt_kernel<<<1024, 256, 0, stream>>>(outw, wout_, 1048576);
    cvt_kernel<<<4096, 256, 0, stream>>>(fcw,  wfc,   4194304);
    cvt_kernel<<<4096, 256, 0, stream>>>(pjw,  wpj,   4194304);

    ln_kernel<<<MROWS, 256, 0, stream>>>(x, ln1w, ln1b, hbuf);

    gemm8_kernel<0><<<64 * 12, 512, 0, stream>>>(hbuf, wip, ipb, nullptr, qkv,
                                                 MROWS, 3072, 1024);

    vtr_kernel<<<32 * 16 * 8, 256, 0, stream>>>(qkv, Vt);

    attn_kernel<<<512, 512, 0, stream>>>(qkv, Vt, ctxb, awout);

    gemm8_kernel<2><<<64 * 4, 512, 0, stream>>>(ctxb, wout_, outb, x, xout,
                                                MROWS, 1024, 1024);

    ln_kernel<<<MROWS, 256, 0, stream>>>(xout, ln2w, ln2b, hbuf);

    gemm8_kernel<1><<<64 * 16, 512, 0, stream>>>(hbuf, wfc, fcb, nullptr, mg,
                                                 MROWS, 4096, 1024);

    gemm8_kernel<2><<<64 * 4, 512, 0, stream>>>(mg, wpj, pjb, xout, xout,
                                                MROWS, 1024, 4096);
}